// Round 4
// baseline (404.613 us; speedup 1.0000x reference)
//
#include <hip/hip_runtime.h>
#include <hip/hip_bf16.h>

typedef __bf16 v8bf __attribute__((ext_vector_type(8)));
typedef __bf16 v4bf __attribute__((ext_vector_type(4)));
typedef float  v4f  __attribute__((ext_vector_type(4)));
typedef float  f32x16 __attribute__((ext_vector_type(16)));

#define AS1 __attribute__((address_space(1)))
#define AS3 __attribute__((address_space(3)))

static __device__ __forceinline__ void gload_lds16(const void* g, void* l) {
  __builtin_amdgcn_global_load_lds((const AS1 void*)g, (AS3 void*)l, 16, 0, 0);
}

// ---- elementwise fp32 -> bf16 (n multiple of 4) ----
__global__ __launch_bounds__(256)
void cvt_bf16(const float* __restrict__ in, __bf16* __restrict__ out, long n) {
  const long i = ((long)blockIdx.x * 256 + threadIdx.x) * 4;
  if (i >= n) return;
  v4f v = *(const v4f*)&in[i];
  v4bf o;
#pragma unroll
  for (int u = 0; u < 4; ++u) o[u] = (__bf16)v[u];
  *(v4bf*)&out[i] = o;
}

// ---- zero fp32 buffer ----
__global__ __launch_bounds__(256)
void zero_f32(float* __restrict__ p, long n) {
  const long i = ((long)blockIdx.x * 256 + threadIdx.x) * 4;
  if (i >= n) return;
  *(v4f*)&p[i] = v4f{0.f, 0.f, 0.f, 0.f};
}

// ---- X [n][c][b] fp32 -> XT [n][b][c] bf16, 64x64 tiles via LDS ----
__global__ __launch_bounds__(256)
void cvt_transpose(const float* __restrict__ X, __bf16* __restrict__ XT) {
  __shared__ float t[64][65];
  const int b0 = blockIdx.x * 64, c0 = blockIdx.y * 64;
  const long n = blockIdx.z;
  const float* Xp = X + n * (1024L * 2048);
  __bf16* Tp = XT + n * (2048L * 1024);
  const int tid = threadIdx.x;
  const int r16 = tid >> 4, c4 = (tid & 15) * 4;
#pragma unroll
  for (int it = 0; it < 4; ++it) {
    const int r = r16 + it * 16;   // local c
    *(v4f*)&t[r][c4] = *(const v4f*)&Xp[(long)(c0 + r) * 2048 + b0 + c4];
  }
  __syncthreads();
  const int rb8 = tid >> 3, c8 = (tid & 7) * 8;
#pragma unroll
  for (int it = 0; it < 2; ++it) {
    const int rb = rb8 + it * 32;  // local b
    v8bf o;
#pragma unroll
    for (int u = 0; u < 8; ++u) o[u] = (__bf16)t[c8 + u][rb];
    *(v8bf*)&Tp[(long)(b0 + rb) * 1024 + c0 + c8] = o;
  }
}

// ---- 256x256 TN GEMM, 32x32x16 MFMA, BK=32, quad-buffered LDS ----
// 8 waves (4x2 qr/qc). Phase = one K-tile of 32: 12 ds_read_b128 + 16 MFMA
// + stage of tile (t+3) into buf (t-1)&3 (4 gloads). Two barriers/phase,
// counted vmcnt(8) every phase (8-12 gloads in flight, never drained).
// LDS swizzle: 16B slot = chunk ^ ((row>>1)&3), via pre-swizzled global src.
// Swapped mfma(B,A): per tile, thread holds ONE row (lane&31), cols in
// reg-quads of 4 consecutive -> vectorized stores + cheap rownorm reduce.
// EPI 0: += bias[col], clamp +-32, atomic rownorm -> dk2[row]
// EPI 1: *= rsqrt(max(dk2[row]*dq2[col],eps)), clamp +-4 ; EPI 2: clamp +-1.
#define BAR __builtin_amdgcn_s_barrier()
#define LGKM0 do { asm volatile("s_waitcnt lgkmcnt(0)" ::: "memory"); \
                   __builtin_amdgcn_sched_barrier(0); } while (0)
#define VMW(N) do { asm volatile("s_waitcnt vmcnt(" #N ")" ::: "memory"); \
                    __builtin_amdgcn_sched_barrier(0); } while (0)
#define MMALL do { \
  __builtin_amdgcn_s_setprio(1); \
  _Pragma("unroll") for (int s = 0; s < 2; ++s) \
  _Pragma("unroll") for (int h = 0; h < 2; ++h) \
  _Pragma("unroll") for (int nb = 0; nb < 4; ++nb) \
    acc[h][nb] = __builtin_amdgcn_mfma_f32_32x32x16_bf16( \
        bf_[nb][s], af[h][s], acc[h][nb], 0, 0, 0); \
  __builtin_amdgcn_s_setprio(0); } while (0)

template<int KD, int EPI, typename OT>
__global__ __launch_bounds__(512, 2)
void gemm256(const __bf16* __restrict__ Abase, const __bf16* __restrict__ Bbase,
             OT* __restrict__ Obase, const __bf16* __restrict__ bias,
             float* __restrict__ dk2, const float* __restrict__ dq2,
             long sA, long sB, long sO) {
  // buffer b (tile t, b=t&3): A[256][32] @ b*16384, B @ b*16384+8192
  __shared__ __align__(128) __bf16 lds[65536];

  const int tid = threadIdx.x;
  const int wave = tid >> 6, lane = tid & 63;
  const int qr = wave >> 1, qc = wave & 1;   // 4x2 wave grid
  const int l31 = lane & 31, hi = lane >> 5;
  const int sw = (l31 >> 1) & 3;             // read-side swizzle key

  // XCD-chunked bijective swizzle (nwg divisible by 8)
  const int gx = gridDim.x, gy = gridDim.y;
  int id = blockIdx.x + gx * (blockIdx.y + gy * blockIdx.z);
  const int chunk8 = (gx * gy * gridDim.z) >> 3;
  id = (id & 7) * chunk8 + (id >> 3);
  const int bx = id % gx;
  const int rem = id / gx;
  const int by = rem % gy;
  const long z = rem / gy;

  const int n0 = bx * 256, m0 = by * 256;
  const __bf16* A = Abase + z * sA + (long)m0 * KD;
  const __bf16* B = Bbase + z * sB + (long)n0 * KD;

  // staging: wave w instr i covers rows [w*32+i*16, +16); lane l -> row
  // +(l>>2), slot l&3 holds source chunk (l&3)^((l>>3)&3) (row>>1 swizzle,
  // base rows are multiples of 16 so only (l>>3)&3 matters). LDS dest linear.
  const int srow = lane >> 2;
  const int schunk = ((lane & 3) ^ ((lane >> 3) & 3)) << 3;
  const __bf16* Alane = A + (long)(wave * 32 + srow) * KD + schunk;
  const __bf16* Blane = B + (long)(wave * 32 + srow) * KD + schunk;
  const int dst = wave * 1024;

  auto stage = [&](int kt) {
    const int bb = (kt & 3) * 16384;
    const __bf16* ga = Alane + kt * 32;
    gload_lds16(ga, lds + bb + dst);
    gload_lds16(ga + (long)16 * KD, lds + bb + dst + 512);
    const __bf16* gb = Blane + kt * 32;
    gload_lds16(gb, lds + bb + 8192 + dst);
    gload_lds16(gb + (long)16 * KD, lds + bb + 8192 + dst + 512);
  };

  f32x16 acc[2][4];
#pragma unroll
  for (int h = 0; h < 2; ++h)
#pragma unroll
    for (int nb = 0; nb < 4; ++nb)
#pragma unroll
      for (int r = 0; r < 16; ++r) acc[h][nb][r] = 0.f;

  v8bf af[2][2], bf_[4][2];
  auto readAB = [&](int buf) {
    const __bf16* sa = lds + buf * 16384;
    const __bf16* sb = sa + 8192;
#pragma unroll
    for (int h = 0; h < 2; ++h)
#pragma unroll
      for (int s = 0; s < 2; ++s)
        af[h][s] = *(const v8bf*)
            &sa[(h * 128 + qr * 32 + l31) * 32 + (((2 * s + hi) ^ sw) << 3)];
#pragma unroll
    for (int nb = 0; nb < 4; ++nb)
#pragma unroll
      for (int s = 0; s < 2; ++s)
        bf_[nb][s] = *(const v8bf*)
            &sb[((nb >> 1) * 128 + qc * 64 + (nb & 1) * 32 + l31) * 32 +
                (((2 * s + hi) ^ sw) << 3)];
  };

  constexpr int NT = KD / 32;
  constexpr int NI = NT / 8;

  // prologue: tiles 0,1,2 (12 gloads); tile 0 done (drain to 8)
  stage(0); stage(1); stage(2);
  VMW(8); BAR;

#pragma unroll 1
  for (int m = 0; m < NI; ++m) {
    const int T = m * 8;
    const bool nl = (m != NI - 1);
#pragma unroll
    for (int q = 0; q < 8; ++q) {
      readAB(q & 3);                      // tile T+q
      if (nl || q <= 4) stage(T + q + 3); // into buf (q-1)&3 (read last phase)
      BAR; LGKM0;
      MMALL;
      if (nl || q <= 4) { VMW(8); }
      else if (q == 5)  { VMW(4); }
      else if (q == 6)  { VMW(0); }
      if (nl || q != 7) BAR;
    }
  }

  // Epilogue. acc[h][nb] reg r: row = m0+h*128+qr*32+l31 (one row/tile),
  // col = n0+(nb>>1)*128+qc*64+(nb&1)*32 + 8*(r>>2)+4*hi + (r&3).
  OT* O = Obase + z * sO;
  const int ldo = gx * 256;
#pragma unroll
  for (int h = 0; h < 2; ++h) {
    const int row = m0 + h * 128 + qr * 32 + l31;
    float rk = 0.f, rs = 0.f;
    if (EPI == 1) rk = dk2[z * 2048 + row];
#pragma unroll
    for (int nb = 0; nb < 4; ++nb) {
#pragma unroll
      for (int t = 0; t < 4; ++t) {
        const int colb = n0 + (nb >> 1) * 128 + qc * 64 + (nb & 1) * 32 +
                         t * 8 + hi * 4;
        float cv[4];
        if (EPI == 0) {
          v4bf bb = *(const v4bf*)&bias[colb];
#pragma unroll
          for (int r = 0; r < 4; ++r) cv[r] = (float)bb[r];
        }
        if (EPI == 1) {
          v4f dd = *(const v4f*)&dq2[z * 2048 + colb];
#pragma unroll
          for (int r = 0; r < 4; ++r) cv[r] = dd[r];
        }
        float vv[4];
#pragma unroll
        for (int r = 0; r < 4; ++r) {
          float v = acc[h][nb][t * 4 + r];
          if (EPI == 0) {
            v = fminf(fmaxf(v + cv[r], -32.f), 32.f);
            rs += v * v;
          }
          if (EPI == 1) {
            v *= rsqrtf(fmaxf(rk * cv[r], 1e-12f));
            v = fminf(fmaxf(v, -4.f), 4.f);
          }
          if (EPI == 2) v = fminf(fmaxf(v, -1.f), 1.f);
          vv[r] = v;
        }
        if (sizeof(OT) == 2) {
          v4bf o;
#pragma unroll
          for (int r = 0; r < 4; ++r) o[r] = (__bf16)vv[r];
          *(v4bf*)&O[(long)row * ldo + colb] = o;
        } else {
          v4f o;
#pragma unroll
          for (int r = 0; r < 4; ++r) o[r] = vv[r];
          *(v4f*)&O[(long)row * ldo + colb] = o;
        }
      }
    }
    if (EPI == 0) {
      rs += __shfl_xor(rs, 32);
      if (hi == 0) atomicAdd(&dk2[z * 2048 + row], rs);
    }
  }
}

// ---- in-place row softmax over 2048 bf16 (|Y|<=4: no max pass) ----
__global__ __launch_bounds__(256)
void softmax_rows(__bf16* __restrict__ Y) {
  const int tid = threadIdx.x;
  const long row = (long)blockIdx.y * gridDim.x + blockIdx.x;
  __bf16* p = Y + row * 2048;
  v8bf v = *(const v8bf*)&p[tid * 8];
  float f[8];
  float s = 0.f;
#pragma unroll
  for (int u = 0; u < 8; ++u) { f[u] = __expf((float)v[u]); s += f[u]; }
#pragma unroll
  for (int off = 32; off > 0; off >>= 1) s += __shfl_down(s, off);
  __shared__ float red[4];
  __shared__ float stot;
  if ((tid & 63) == 0) red[tid >> 6] = s;
  __syncthreads();
  if (tid == 0) stot = 1.f / (red[0] + red[1] + red[2] + red[3]);
  __syncthreads();
  const float inv = stot;
  v8bf o;
#pragma unroll
  for (int u = 0; u < 8; ++u) o[u] = (__bf16)(f[u] * inv);
  *(v8bf*)&p[tid * 8] = o;
}

extern "C" void kernel_launch(void* const* d_in, const int* in_sizes, int n_in,
                              void* d_out, int out_size, void* d_ws, size_t ws_size,
                              hipStream_t stream) {
  const float* X    = (const float*)d_in[0];
  const float* Wk_w = (const float*)d_in[1];
  const float* Wk_b = (const float*)d_in[2];
  const float* Wq_w = (const float*)d_in[3];
  const float* Wq_b = (const float*)d_in[4];
  float* out = (float*)d_out;

  // ws: [0,32M): XT bf16 [n][b][c] -> later Xbf bf16 [n][c][b]
  //     [32M,96M): YT bf16 [n][k][b]
  //     [96M+): DK2, DQ2, Wk_bf, Wq_bf, bk_bf, bq_bf
  char* ws = (char*)d_ws;
  __bf16* XT  = (__bf16*)(ws);
  __bf16* Xbf = (__bf16*)(ws);
  __bf16* YT  = (__bf16*)(ws + 33554432L);
  char* aux   = ws + 100663296L;
  float*  DK2   = (float*)(aux);
  float*  DQ2   = (float*)(aux + 65536L);
  __bf16* Wk_bf = (__bf16*)(aux + 131072L);
  __bf16* Wq_bf = (__bf16*)(aux + 131072L + 2097152L);
  __bf16* bk_bf = (__bf16*)(aux + 131072L + 4194304L);
  __bf16* bq_bf = (__bf16*)(aux + 131072L + 4196352L);
  // d_out (64 MiB) holds KT|QT until GEMM3 overwrites it with Z.
  __bf16* KT = (__bf16*)d_out;
  __bf16* QT = (__bf16*)((char*)d_out + 33554432L);

  // 0) convert weights/biases to bf16; zero DK2|DQ2 (contiguous 128 KiB)
  cvt_bf16<<<1024, 256, 0, stream>>>(Wk_w, Wk_bf, 1048576L);
  cvt_bf16<<<1024, 256, 0, stream>>>(Wq_w, Wq_bf, 1048576L);
  cvt_bf16<<<1, 256, 0, stream>>>(Wk_b, bk_bf, 1024L);
  cvt_bf16<<<1, 256, 0, stream>>>(Wq_b, bq_bf, 1024L);
  zero_f32<<<32, 256, 0, stream>>>(DK2, 32768L);
  // 1) XT[n][b][c] = (bf16) X[n][c][b]
  cvt_transpose<<<dim3(32, 16, 8), 256, 0, stream>>>(X, XT);
  // 2) KT[n][b][o] = XT[b,:]·Wk[o,:] + bk[o]; fused rownorm -> DK2; same for Q
  gemm256<1024, 0, __bf16><<<dim3(4, 8, 8), 512, 0, stream>>>(
      XT, Wk_bf, KT, bk_bf, DK2, nullptr, 2048L * 1024, 0L, 2048L * 1024);
  gemm256<1024, 0, __bf16><<<dim3(4, 8, 8), 512, 0, stream>>>(
      XT, Wq_bf, QT, bq_bf, DQ2, nullptr, 2048L * 1024, 0L, 2048L * 1024);
  // 3) Xbf = (bf16) X  (XT dead; same ws region)
  cvt_bf16<<<16384, 256, 0, stream>>>(X, Xbf, 16777216L);
  // 4) YT[n][k][b] = (KT[k,:]·QT[b,:]) * rsqrt(max(DK2[k]*DQ2[b],eps))
  gemm256<1024, 1, __bf16><<<dim3(8, 8, 8), 512, 0, stream>>>(
      KT, QT, YT, nullptr, DK2, DQ2, 2048L * 1024, 2048L * 1024, 2048L * 2048);
  // 5) softmax over b within each YT row (ref softmax over query axis)
  softmax_rows<<<dim3(2048, 8), 256, 0, stream>>>(YT);
  // 6) Z[n][c][k] = Xbf[c,:]·SMT[k,:]  (sum over b) -> d_out fp32
  gemm256<2048, 2, float><<<dim3(8, 4, 8), 512, 0, stream>>>(
      Xbf, YT, out, nullptr, nullptr, nullptr, 1024L * 2048, 2048L * 2048, 1024L * 2048);
}

// Round 5
// 396.869 us; speedup vs baseline: 1.0195x; 1.0195x over previous
//
#include <hip/hip_runtime.h>
#include <hip/hip_bf16.h>

typedef __bf16 v8bf __attribute__((ext_vector_type(8)));
typedef __bf16 v4bf __attribute__((ext_vector_type(4)));
typedef float  v4f  __attribute__((ext_vector_type(4)));
typedef float  f32x16 __attribute__((ext_vector_type(16)));

#define AS1 __attribute__((address_space(1)))
#define AS3 __attribute__((address_space(3)))

static __device__ __forceinline__ void gload_lds16(const void* g, void* l) {
  __builtin_amdgcn_global_load_lds((const AS1 void*)g, (AS3 void*)l, 16, 0, 0);
}

// ---- elementwise fp32 -> bf16 (n multiple of 4) ----
__global__ __launch_bounds__(256)
void cvt_bf16(const float* __restrict__ in, __bf16* __restrict__ out, long n) {
  const long i = ((long)blockIdx.x * 256 + threadIdx.x) * 4;
  if (i >= n) return;
  v4f v = *(const v4f*)&in[i];
  v4bf o;
#pragma unroll
  for (int u = 0; u < 4; ++u) o[u] = (__bf16)v[u];
  *(v4bf*)&out[i] = o;
}

// ---- zero fp32 buffer ----
__global__ __launch_bounds__(256)
void zero_f32(float* __restrict__ p, long n) {
  const long i = ((long)blockIdx.x * 256 + threadIdx.x) * 4;
  if (i >= n) return;
  *(v4f*)&p[i] = v4f{0.f, 0.f, 0.f, 0.f};
}

// ---- X [n][c][b] fp32 -> XT [n][b][c] bf16, 64x64 tiles via LDS ----
__global__ __launch_bounds__(256)
void cvt_transpose(const float* __restrict__ X, __bf16* __restrict__ XT) {
  __shared__ float t[64][65];
  const int b0 = blockIdx.x * 64, c0 = blockIdx.y * 64;
  const long n = blockIdx.z;
  const float* Xp = X + n * (1024L * 2048);
  __bf16* Tp = XT + n * (2048L * 1024);
  const int tid = threadIdx.x;
  const int r16 = tid >> 4, c4 = (tid & 15) * 4;
#pragma unroll
  for (int it = 0; it < 4; ++it) {
    const int r = r16 + it * 16;   // local c
    *(v4f*)&t[r][c4] = *(const v4f*)&Xp[(long)(c0 + r) * 2048 + b0 + c4];
  }
  __syncthreads();
  const int rb8 = tid >> 3, c8 = (tid & 7) * 8;
#pragma unroll
  for (int it = 0; it < 2; ++it) {
    const int rb = rb8 + it * 32;  // local b
    v8bf o;
#pragma unroll
    for (int u = 0; u < 8; ++u) o[u] = (__bf16)t[c8 + u][rb];
    *(v8bf*)&Tp[(long)(b0 + rb) * 1024 + c0 + c8] = o;
  }
}

// ---- 256x256 TN GEMM, 32x32x16 MFMA on the R3 BK=64 layout ----
// 8 waves (4x2 qr/qc), double-buffered LDS (128 KiB), 8 phases / 2 K-tiles.
// LDS layout & swizzle IDENTICAL to R3 (measured conflict-free): row stride
// 64 elems (128B); 16B slot s of row r holds k-chunk s^(r&7); staged via
// pre-swizzled global source, linear LDS dest.
// Per phase: [ds_read one fragment set][stage one half-tile (2 gloads)]
//            [lgkmcnt(0)][vmcnt(6) at ph4/8][BAR][setprio 8x MFMA 32x32x16].
// A fragments held in regs across phases -> no re-read (24 reads/K-tile/wave).
// Swapped mfma(B,A): lane holds ONE output row (l31); 16 regs sweep cols.
// EPI 0: += bias[col], clamp +-32, atomic rownorm -> dk2[row]
// EPI 1: *= rsqrt(max(dk2[row]*dq2[col],eps)), clamp +-4 ; EPI 2: clamp +-1.
#define BAR __builtin_amdgcn_s_barrier()
#define LGKM0 do { asm volatile("s_waitcnt lgkmcnt(0)" ::: "memory"); \
                   __builtin_amdgcn_sched_barrier(0); } while (0)
#define VMW(N) do { asm volatile("s_waitcnt vmcnt(" #N ")" ::: "memory"); \
                    __builtin_amdgcn_sched_barrier(0); } while (0)
// one phase's MFMA: 4 k-steps x 2 col-tiles into acc[HM][2*NP+j]
#define MM(AF, HM, NP) do { \
  __builtin_amdgcn_s_setprio(1); \
  _Pragma("unroll") for (int ks = 0; ks < 4; ++ks) \
  _Pragma("unroll") for (int j = 0; j < 2; ++j) \
    acc[HM][2 * (NP) + j] = __builtin_amdgcn_mfma_f32_32x32x16_bf16( \
        bfr[j][ks], AF[ks], acc[HM][2 * (NP) + j], 0, 0, 0); \
  __builtin_amdgcn_s_setprio(0); } while (0)

template<int KD, int EPI, typename OT>
__global__ __launch_bounds__(512, 2)
void gemm256(const __bf16* __restrict__ Abase, const __bf16* __restrict__ Bbase,
             OT* __restrict__ Obase, const __bf16* __restrict__ bias,
             float* __restrict__ dk2, const float* __restrict__ dq2,
             long sA, long sB, long sO) {
  // buf0 (even tiles): A[256][64] @0, B @16384; buf1 (odd tiles) @32768.
  __shared__ __align__(128) __bf16 lds[65536];

  const int tid = threadIdx.x;
  const int wave = tid >> 6, lane = tid & 63;
  const int qr = wave >> 1, qc = wave & 1;   // 4x2 wave grid
  const int l31 = lane & 31, hi = lane >> 5;
  const int k7 = l31 & 7;                    // read-side swizzle key

  // XCD-chunked bijective swizzle (nwg divisible by 8)
  const int gx = gridDim.x, gy = gridDim.y;
  int id = blockIdx.x + gx * (blockIdx.y + gy * blockIdx.z);
  const int chunk8 = (gx * gy * gridDim.z) >> 3;
  id = (id & 7) * chunk8 + (id >> 3);
  const int bx = id % gx;
  const int rem = id / gx;
  const int by = rem % gy;
  const long z = rem / gy;

  const int n0 = bx * 256, m0 = by * 256;
  const __bf16* A = Abase + z * sA + (long)m0 * KD;
  const __bf16* B = Bbase + z * sB + (long)n0 * KD;

  // staging (identical to R3): wave w, instr i covers rows [half*128+w*16+i*8);
  // lane l -> row +(l>>3), slot (l&7) holds k-chunk ((l&7)^(l>>3)).
  const int lrow = wave * 16 + (lane >> 3);
  const int lchunk = ((lane & 7) ^ (lane >> 3)) << 3;
  const __bf16* Alane = A + (long)lrow * KD + lchunk;
  const __bf16* Blane = B + (long)lrow * KD + lchunk;
  const int dbase = wave * 1024;

  auto stage = [&](int kt, int isB, int half) {
    const __bf16* gp = (isB ? Blane : Alane) + (long)(half * 128) * KD + kt * 64;
    __bf16* dp = lds + (kt & 1) * 32768 + isB * 16384 + half * 8192 + dbase;
    gload_lds16(gp, dp);
    gload_lds16(gp + (long)8 * KD, dp + 512);
  };

  f32x16 acc[2][4];
#pragma unroll
  for (int h = 0; h < 2; ++h)
#pragma unroll
    for (int nb = 0; nb < 4; ++nb)
#pragma unroll
      for (int r = 0; r < 16; ++r) acc[h][nb][r] = 0.f;

  // fragment regs: af0 persists ph1->ph4; af1 ph2->ph3; bfr reused ph1/ph3.
  v8bf af0[4], af1[4], bfr[2][4];
  // A fragment set for row-half hm (4 b128): row = hm*128+qr*32+l31
  auto readA = [&](const __bf16* buf, int hm, v8bf* dst) {
    const __bf16* sa = buf + hm * 8192 + (qr * 32 + l31) * 64;
#pragma unroll
    for (int ks = 0; ks < 4; ++ks)
      dst[ks] = *(const v8bf*)&sa[((2 * ks + hi) ^ k7) << 3];
  };
  // B fragment pair for col-half np (8 b128): col = np*128+qc*64+j*32+l31
  auto readB = [&](const __bf16* buf, int np) {
#pragma unroll
    for (int j = 0; j < 2; ++j) {
      const __bf16* sb = buf + 16384 + np * 8192 + (qc * 64 + j * 32 + l31) * 64;
#pragma unroll
      for (int ks = 0; ks < 4; ++ks)
        bfr[j][ks] = *(const v8bf*)&sb[((2 * ks + hi) ^ k7) << 3];
    }
  };

  constexpr int NT = KD / 64;
  constexpr int NI = NT / 2;
  __bf16* s0 = lds;
  __bf16* s1 = lds + 32768;

  // prologue: tile0 all 4 halves + tile1 {B0,A1,B1}; tile1.A0 is JIT at ph1.
  stage(0, 0, 0); stage(0, 1, 0); stage(0, 0, 1); stage(0, 1, 1);
  stage(1, 1, 0); stage(1, 0, 1); stage(1, 1, 1);
  VMW(6); BAR;

#pragma unroll 1
  for (int m = 0; m < NI; ++m) {
    const bool nl = (m != NI - 1);
    const int t1 = 2 * m + 1, t2 = 2 * m + 2, t3 = 2 * m + 3;
    // ph1: read s0.A0 + s0.B-half0 ; stage s1.A0 (t1, JIT)
    readA(s0, 0, af0); readB(s0, 0);
    stage(t1, 0, 0);
    LGKM0; BAR; MM(af0, 0, 0);
    // ph2: read s0.A1 (bfr held); stage s0.B0 (t2)
    readA(s0, 1, af1);
    if (nl) stage(t2, 1, 0);
    LGKM0; BAR; MM(af1, 1, 0);
    // ph3: read s0.B-half1 (af1 held); stage s0.A1 (t2)
    readB(s0, 1);
    if (nl) stage(t2, 0, 1);
    LGKM0; BAR; MM(af1, 1, 1);
    // ph4: no reads (af0,bfr held); stage s0.B1 (t2); counted vmcnt
    if (nl) stage(t2, 1, 1);
    if (nl) { VMW(6); } else { VMW(0); }
    BAR; MM(af0, 0, 1);
    // ph5: read s1.A0 + s1.B-half0 ; stage s0.A0 (t2)
    readA(s1, 0, af0); readB(s1, 0);
    if (nl) stage(t2, 0, 0);
    LGKM0; BAR; MM(af0, 0, 0);
    // ph6: read s1.A1 ; stage s1.B0 (t3)
    readA(s1, 1, af1);
    if (nl) stage(t3, 1, 0);
    LGKM0; BAR; MM(af1, 1, 0);
    // ph7: read s1.B-half1 ; stage s1.A1 (t3)
    readB(s1, 1);
    if (nl) stage(t3, 0, 1);
    LGKM0; BAR; MM(af1, 1, 1);
    // ph8: no reads ; stage s1.B1 (t3); counted vmcnt
    if (nl) stage(t3, 1, 1);
    if (nl) { VMW(6); } else { VMW(0); }
    BAR; MM(af0, 0, 1);
  }

  // Epilogue (R4-verified 32x32 layout): acc[h][nb] reg r:
  //   row = m0 + h*128 + qr*32 + l31
  //   col = n0 + (nb>>1)*128 + qc*64 + (nb&1)*32 + 8*(r>>2) + 4*hi + (r&3)
  OT* O = Obase + z * sO;
  const int ldo = gx * 256;
#pragma unroll
  for (int h = 0; h < 2; ++h) {
    const int row = m0 + h * 128 + qr * 32 + l31;
    float rk = 0.f, rs = 0.f;
    if (EPI == 1) rk = dk2[z * 2048 + row];
#pragma unroll
    for (int nb = 0; nb < 4; ++nb) {
#pragma unroll
      for (int t = 0; t < 4; ++t) {
        const int colb = n0 + (nb >> 1) * 128 + qc * 64 + (nb & 1) * 32 +
                         t * 8 + hi * 4;
        float cv[4];
        if (EPI == 0) {
          v4bf bb = *(const v4bf*)&bias[colb];
#pragma unroll
          for (int r = 0; r < 4; ++r) cv[r] = (float)bb[r];
        }
        if (EPI == 1) {
          v4f dd = *(const v4f*)&dq2[z * 2048 + colb];
#pragma unroll
          for (int r = 0; r < 4; ++r) cv[r] = dd[r];
        }
        float vv[4];
#pragma unroll
        for (int r = 0; r < 4; ++r) {
          float v = acc[h][nb][t * 4 + r];
          if (EPI == 0) {
            v = fminf(fmaxf(v + cv[r], -32.f), 32.f);
            rs += v * v;
          }
          if (EPI == 1) {
            v *= rsqrtf(fmaxf(rk * cv[r], 1e-12f));
            v = fminf(fmaxf(v, -4.f), 4.f);
          }
          if (EPI == 2) v = fminf(fmaxf(v, -1.f), 1.f);
          vv[r] = v;
        }
        if (sizeof(OT) == 2) {
          v4bf o;
#pragma unroll
          for (int r = 0; r < 4; ++r) o[r] = (__bf16)vv[r];
          *(v4bf*)&O[(long)row * ldo + colb] = o;
        } else {
          v4f o;
#pragma unroll
          for (int r = 0; r < 4; ++r) o[r] = vv[r];
          *(v4f*)&O[(long)row * ldo + colb] = o;
        }
      }
    }
    if (EPI == 0) {
      rs += __shfl_xor(rs, 32);
      if (hi == 0) atomicAdd(&dk2[z * 2048 + row], rs);
    }
  }
}

// ---- in-place row softmax over 2048 bf16 (|Y|<=4: no max pass) ----
__global__ __launch_bounds__(256)
void softmax_rows(__bf16* __restrict__ Y) {
  const int tid = threadIdx.x;
  const long row = (long)blockIdx.y * gridDim.x + blockIdx.x;
  __bf16* p = Y + row * 2048;
  v8bf v = *(const v8bf*)&p[tid * 8];
  float f[8];
  float s = 0.f;
#pragma unroll
  for (int u = 0; u < 8; ++u) { f[u] = __expf((float)v[u]); s += f[u]; }
#pragma unroll
  for (int off = 32; off > 0; off >>= 1) s += __shfl_down(s, off);
  __shared__ float red[4];
  __shared__ float stot;
  if ((tid & 63) == 0) red[tid >> 6] = s;
  __syncthreads();
  if (tid == 0) stot = 1.f / (red[0] + red[1] + red[2] + red[3]);
  __syncthreads();
  const float inv = stot;
  v8bf o;
#pragma unroll
  for (int u = 0; u < 8; ++u) o[u] = (__bf16)(f[u] * inv);
  *(v8bf*)&p[tid * 8] = o;
}

extern "C" void kernel_launch(void* const* d_in, const int* in_sizes, int n_in,
                              void* d_out, int out_size, void* d_ws, size_t ws_size,
                              hipStream_t stream) {
  const float* X    = (const float*)d_in[0];
  const float* Wk_w = (const float*)d_in[1];
  const float* Wk_b = (const float*)d_in[2];
  const float* Wq_w = (const float*)d_in[3];
  const float* Wq_b = (const float*)d_in[4];
  float* out = (float*)d_out;

  // ws: [0,32M): XT bf16 [n][b][c] -> later Xbf bf16 [n][c][b]
  //     [32M,96M): YT bf16 [n][k][b]
  //     [96M+): DK2, DQ2, Wk_bf, Wq_bf, bk_bf, bq_bf
  char* ws = (char*)d_ws;
  __bf16* XT  = (__bf16*)(ws);
  __bf16* Xbf = (__bf16*)(ws);
  __bf16* YT  = (__bf16*)(ws + 33554432L);
  char* aux   = ws + 100663296L;
  float*  DK2   = (float*)(aux);
  float*  DQ2   = (float*)(aux + 65536L);
  __bf16* Wk_bf = (__bf16*)(aux + 131072L);
  __bf16* Wq_bf = (__bf16*)(aux + 131072L + 2097152L);
  __bf16* bk_bf = (__bf16*)(aux + 131072L + 4194304L);
  __bf16* bq_bf = (__bf16*)(aux + 131072L + 4196352L);
  // d_out (64 MiB) holds KT|QT until GEMM3 overwrites it with Z.
  __bf16* KT = (__bf16*)d_out;
  __bf16* QT = (__bf16*)((char*)d_out + 33554432L);

  // 0) convert weights/biases to bf16; zero DK2|DQ2 (contiguous 128 KiB)
  cvt_bf16<<<1024, 256, 0, stream>>>(Wk_w, Wk_bf, 1048576L);
  cvt_bf16<<<1024, 256, 0, stream>>>(Wq_w, Wq_bf, 1048576L);
  cvt_bf16<<<1, 256, 0, stream>>>(Wk_b, bk_bf, 1024L);
  cvt_bf16<<<1, 256, 0, stream>>>(Wq_b, bq_bf, 1024L);
  zero_f32<<<32, 256, 0, stream>>>(DK2, 32768L);
  // 1) XT[n][b][c] = (bf16) X[n][c][b]
  cvt_transpose<<<dim3(32, 16, 8), 256, 0, stream>>>(X, XT);
  // 2) KT[n][b][o] = XT[b,:]·Wk[o,:] + bk[o]; fused rownorm -> DK2; same for Q
  gemm256<1024, 0, __bf16><<<dim3(4, 8, 8), 512, 0, stream>>>(
      XT, Wk_bf, KT, bk_bf, DK2, nullptr, 2048L * 1024, 0L, 2048L * 1024);
  gemm256<1024, 0, __bf16><<<dim3(4, 8, 8), 512, 0, stream>>>(
      XT, Wq_bf, QT, bq_bf, DQ2, nullptr, 2048L * 1024, 0L, 2048L * 1024);
  // 3) Xbf = (bf16) X  (XT dead; same ws region)
  cvt_bf16<<<16384, 256, 0, stream>>>(X, Xbf, 16777216L);
  // 4) YT[n][k][b] = (KT[k,:]·QT[b,:]) * rsqrt(max(DK2[k]*DQ2[b],eps))
  gemm256<1024, 1, __bf16><<<dim3(8, 8, 8), 512, 0, stream>>>(
      KT, QT, YT, nullptr, DK2, DQ2, 2048L * 1024, 2048L * 1024, 2048L * 2048);
  // 5) softmax over b within each YT row (ref softmax over query axis)
  softmax_rows<<<dim3(2048, 8), 256, 0, stream>>>(YT);
  // 6) Z[n][c][k] = Xbf[c,:]·SMT[k,:]  (sum over b) -> d_out fp32
  gemm256<2048, 2, float><<<dim3(8, 4, 8), 512, 0, stream>>>(
      Xbf, YT, out, nullptr, nullptr, nullptr, 1024L * 2048, 2048L * 2048, 1024L * 2048);
}

// Round 6
// 352.739 us; speedup vs baseline: 1.1471x; 1.1251x over previous
//
#include <hip/hip_runtime.h>
#include <hip/hip_bf16.h>

typedef __bf16 v8bf __attribute__((ext_vector_type(8)));
typedef __bf16 v4bf __attribute__((ext_vector_type(4)));
typedef float  v4f  __attribute__((ext_vector_type(4)));

#define AS1 __attribute__((address_space(1)))
#define AS3 __attribute__((address_space(3)))

static __device__ __forceinline__ void gload_lds16(const void* g, void* l) {
  __builtin_amdgcn_global_load_lds((const AS1 void*)g, (AS3 void*)l, 16, 0, 0);
}

// ---- elementwise fp32 -> bf16 (n multiple of 4) ----
__global__ __launch_bounds__(256)
void cvt_bf16(const float* __restrict__ in, __bf16* __restrict__ out, long n) {
  const long i = ((long)blockIdx.x * 256 + threadIdx.x) * 4;
  if (i >= n) return;
  v4f v = *(const v4f*)&in[i];
  v4bf o;
#pragma unroll
  for (int u = 0; u < 4; ++u) o[u] = (__bf16)v[u];
  *(v4bf*)&out[i] = o;
}

// ---- zero fp32 buffer ----
__global__ __launch_bounds__(256)
void zero_f32(float* __restrict__ p, long n) {
  const long i = ((long)blockIdx.x * 256 + threadIdx.x) * 4;
  if (i >= n) return;
  *(v4f*)&p[i] = v4f{0.f, 0.f, 0.f, 0.f};
}

// ---- X [n][c][b] fp32 -> XT [n][b][c] bf16, 64x64 tiles via LDS ----
__global__ __launch_bounds__(256)
void cvt_transpose(const float* __restrict__ X, __bf16* __restrict__ XT) {
  __shared__ float t[64][65];
  const int b0 = blockIdx.x * 64, c0 = blockIdx.y * 64;
  const long n = blockIdx.z;
  const float* Xp = X + n * (1024L * 2048);
  __bf16* Tp = XT + n * (2048L * 1024);
  const int tid = threadIdx.x;
  const int r16 = tid >> 4, c4 = (tid & 15) * 4;
#pragma unroll
  for (int it = 0; it < 4; ++it) {
    const int r = r16 + it * 16;   // local c
    *(v4f*)&t[r][c4] = *(const v4f*)&Xp[(long)(c0 + r) * 2048 + b0 + c4];
  }
  __syncthreads();
  const int rb8 = tid >> 3, c8 = (tid & 7) * 8;
#pragma unroll
  for (int it = 0; it < 2; ++it) {
    const int rb = rb8 + it * 32;  // local b
    v8bf o;
#pragma unroll
    for (int u = 0; u < 8; ++u) o[u] = (__bf16)t[c8 + u][rb];
    *(v8bf*)&Tp[(long)(b0 + rb) * 1024 + c0 + c8] = o;
  }
}

// ---- 256x256 TN GEMM, 8-phase (R3-verified core), counted vmcnt ----
// 8 waves (4x2 qr/qc), BK=64, double-buffered LDS (128 KiB), XOR-swizzle
// (slot s of row r holds k-chunk s^(r&7); pre-swizzled global src, linear
// LDS dest; fr/q fragment read pattern = MEASURED 0 bank conflicts).
// A fragments held in af0/af1 across phases -> ph4/ph8 have no ds_reads
// (24 ds_read_b128 per K-tile/wave). vmcnt(6) at ph4/8 only.
// Swapped mfma(B,A): acc reg-quad = 4 consecutive cols -> vector stores.
// EPI 0: += bias[col], clamp +-32; fused rownorm -> dk2[row] (atomic)
// EPI 1: *= rsqrt(max(dk2[row]*dq2[col],eps)), clamp +-4, store exp();
//        fused row-sum of bf16(exp) -> snorm[row] (atomic)
// EPI 2: /= dq2[col] (the softmax denominator), clamp +-1.
#define BAR __builtin_amdgcn_s_barrier()
#define LGKM0 do { asm volatile("s_waitcnt lgkmcnt(0)" ::: "memory"); \
                   __builtin_amdgcn_sched_barrier(0); } while (0)
#define VMW(N) do { asm volatile("s_waitcnt vmcnt(" #N ")" ::: "memory"); \
                    __builtin_amdgcn_sched_barrier(0); } while (0)
#define MM(AF, HM, HN) do { \
  __builtin_amdgcn_s_setprio(1); \
  _Pragma("unroll") for (int ks = 0; ks < 2; ++ks) \
  _Pragma("unroll") for (int u = 0; u < 2; ++u) \
  _Pragma("unroll") for (int j = 0; j < 4; ++j) \
    acc[2 * (HM) + u][4 * (HN) + j] = __builtin_amdgcn_mfma_f32_16x16x32_bf16( \
        bfr[j][ks], AF[u][ks], acc[2 * (HM) + u][4 * (HN) + j], 0, 0, 0); \
  __builtin_amdgcn_s_setprio(0); } while (0)

template<int KD, int EPI, typename OT>
__global__ __launch_bounds__(512, 2)
void gemm256(const __bf16* __restrict__ Abase, const __bf16* __restrict__ Bbase,
             OT* __restrict__ Obase, const __bf16* __restrict__ bias,
             float* __restrict__ dk2, const float* __restrict__ dq2,
             float* __restrict__ snorm,
             long sA, long sB, long sO) {
  // buf0 (even tiles): A[256][64] @0, B @16384; buf1 (odd tiles) @32768.
  __shared__ __align__(128) __bf16 lds[65536];

  const int tid = threadIdx.x;
  const int wave = tid >> 6, lane = tid & 63;
  const int qr = wave >> 1, qc = wave & 1;   // 4x2 wave grid
  const int fr = lane & 15, q = lane >> 4;
  const int f7 = fr & 7;

  // XCD-chunked bijective swizzle (nwg divisible by 8)
  const int gx = gridDim.x, gy = gridDim.y;
  int id = blockIdx.x + gx * (blockIdx.y + gy * blockIdx.z);
  const int chunk8 = (gx * gy * gridDim.z) >> 3;
  id = (id & 7) * chunk8 + (id >> 3);
  const int bx = id % gx;
  const int rem = id / gx;
  const int by = rem % gy;
  const long z = rem / gy;

  const int n0 = bx * 256, m0 = by * 256;
  const __bf16* A = Abase + z * sA + (long)m0 * KD;
  const __bf16* B = Bbase + z * sB + (long)n0 * KD;

  // staging: wave w, instr i covers rows [half*128+w*16+i*8, +8);
  // lane l -> row +(l>>3), slot (l&7) holds k-chunk ((l&7)^(l>>3)).
  const int lrow = wave * 16 + (lane >> 3);
  const int lchunk = ((lane & 7) ^ (lane >> 3)) << 3;
  const __bf16* Alane = A + (long)lrow * KD + lchunk;
  const __bf16* Blane = B + (long)lrow * KD + lchunk;
  const int dbase = wave * 1024;

  auto stage = [&](int kt, int isB, int half) {
    const __bf16* gp = (isB ? Blane : Alane) + (long)(half * 128) * KD + kt * 64;
    __bf16* dp = lds + (kt & 1) * 32768 + isB * 16384 + half * 8192 + dbase;
    gload_lds16(gp, dp);
    gload_lds16(gp + (long)8 * KD, dp + 512);
  };

  v4f acc[4][8];
#pragma unroll
  for (int i = 0; i < 4; ++i)
#pragma unroll
    for (int j = 0; j < 8; ++j) acc[i][j] = {0.f, 0.f, 0.f, 0.f};

  v8bf af0[2][2], af1[2][2], bfr[4][2];
  auto readA = [&](const __bf16* sa, int hm, v8bf (&dst)[2][2]) {
#pragma unroll
    for (int u = 0; u < 2; ++u) {
      const int rb = (hm * 128 + qr * 32 + u * 16 + fr) * 64;
      dst[u][0] = *(const v8bf*)&sa[rb + ((q ^ f7) << 3)];
      dst[u][1] = *(const v8bf*)&sa[rb + (((q | 4) ^ f7) << 3)];
    }
  };
  auto readB = [&](const __bf16* sb, int hn) {
#pragma unroll
    for (int j = 0; j < 4; ++j) {
      const int rb = (hn * 128 + qc * 64 + j * 16 + fr) * 64;
      bfr[j][0] = *(const v8bf*)&sb[rb + ((q ^ f7) << 3)];
      bfr[j][1] = *(const v8bf*)&sb[rb + (((q | 4) ^ f7) << 3)];
    }
  };

  constexpr int NT = KD / 64;
  constexpr int NI = NT / 2;
  __bf16* s0 = lds;
  __bf16* s1 = lds + 32768;

  // prologue: tile0 all 4 halves + tile1 {B0,A1,B1}; tile1.A0 is JIT at ph1.
  stage(0, 0, 0); stage(0, 1, 0); stage(0, 0, 1); stage(0, 1, 1);
  stage(1, 1, 0); stage(1, 0, 1); stage(1, 1, 1);
  VMW(6); BAR;

#pragma unroll 1
  for (int m = 0; m < NI; ++m) {
    const bool nl = (m != NI - 1);
    const int t1 = 2 * m + 1, t2 = 2 * m + 2, t3 = 2 * m + 3;
    // ph1: reads s0.A0 -> af0, s0.B-half0 ; stage s1.A0 (t1, JIT)
    readA(s0, 0, af0); readB(s0 + 16384, 0);
    stage(t1, 0, 0);
    LGKM0; BAR; MM(af0, 0, 0);
    // ph2: reads s0.A1 -> af1 (bfr held); stage s0.B0 (t2)
    readA(s0, 1, af1);
    if (nl) stage(t2, 1, 0);
    LGKM0; BAR; MM(af1, 1, 0);
    // ph3: reads s0.B-half1 (af1 held); stage s0.A1 (t2)
    readB(s0 + 16384, 1);
    if (nl) stage(t2, 0, 1);
    LGKM0; BAR; MM(af1, 1, 1);
    // ph4: NO ds_reads (af0, bfr held); stage s0.B1 (t2); counted vmcnt
    if (nl) stage(t2, 1, 1);
    if (nl) { VMW(6); } else { VMW(0); }
    BAR; MM(af0, 0, 1);
    // ph5: reads s1.A0 -> af0, s1.B-half0 ; stage s0.A0 (t2)
    readA(s1, 0, af0); readB(s1 + 16384, 0);
    if (nl) stage(t2, 0, 0);
    LGKM0; BAR; MM(af0, 0, 0);
    // ph6: reads s1.A1 -> af1 ; stage s1.B0 (t3)
    readA(s1, 1, af1);
    if (nl) stage(t3, 1, 0);
    LGKM0; BAR; MM(af1, 1, 0);
    // ph7: reads s1.B-half1 ; stage s1.A1 (t3)
    readB(s1 + 16384, 1);
    if (nl) stage(t3, 0, 1);
    LGKM0; BAR; MM(af1, 1, 1);
    // ph8: NO ds_reads ; stage s1.B1 (t3); counted vmcnt
    if (nl) stage(t3, 1, 1);
    if (nl) { VMW(6); } else { VMW(0); }
    BAR; MM(af0, 0, 1);
  }

  // Epilogue. acc[ai][bj] reg r:
  //   row = m0 + (ai>>1)*128 + qr*32 + (ai&1)*16 + fr
  //   col = n0 + (bj>>2)*128 + qc*64 + (bj&3)*16 + q*4 + r  (r contiguous)
  OT* O = Obase + z * sO;
  const int ldo = gx * 256;
#pragma unroll
  for (int ai = 0; ai < 4; ++ai) {
    const int row = m0 + (ai >> 1) * 128 + qr * 32 + (ai & 1) * 16 + fr;
    float rk = 0.f, rs = 0.f;
    if (EPI == 1) rk = dk2[z * 2048 + row];
#pragma unroll
    for (int bj = 0; bj < 8; ++bj) {
      const int colb = n0 + (bj >> 2) * 128 + qc * 64 + (bj & 3) * 16 + q * 4;
      float cv[4];
      if (EPI == 0) {
        v4bf bb = *(const v4bf*)&bias[colb];
#pragma unroll
        for (int r = 0; r < 4; ++r) cv[r] = (float)bb[r];
      }
      if (EPI == 1 || EPI == 2) {
        v4f dd = *(const v4f*)&dq2[z * 2048 + colb];
#pragma unroll
        for (int r = 0; r < 4; ++r) cv[r] = dd[r];
      }
      float vv[4];
#pragma unroll
      for (int r = 0; r < 4; ++r) {
        float v = acc[ai][bj][r];
        if (EPI == 0) {
          v = fminf(fmaxf(v + cv[r], -32.f), 32.f);
          rs += v * v;
        }
        if (EPI == 1) {
          v *= rsqrtf(fmaxf(rk * cv[r], 1e-12f));
          v = fminf(fmaxf(v, -4.f), 4.f);
          v = __expf(v);
        }
        if (EPI == 2) {
          v = v / cv[r];
          v = fminf(fmaxf(v, -1.f), 1.f);
        }
        vv[r] = v;
      }
      if (sizeof(OT) == 2) {
        v4bf o;
#pragma unroll
        for (int r = 0; r < 4; ++r) o[r] = (__bf16)vv[r];
        if (EPI == 1) {
#pragma unroll
          for (int r = 0; r < 4; ++r) rs += (float)o[r];  // denom = sum of stored bf16
        }
        *(v4bf*)&O[(long)row * ldo + colb] = o;
      } else {
        v4f o;
#pragma unroll
        for (int r = 0; r < 4; ++r) o[r] = vv[r];
        *(v4f*)&O[(long)row * ldo + colb] = o;
      }
    }
    if (EPI == 0) {
      rs += __shfl_xor(rs, 16);
      rs += __shfl_xor(rs, 32);
      if (q == 0) atomicAdd(&dk2[z * 2048 + row], rs);
    }
    if (EPI == 1) {
      rs += __shfl_xor(rs, 16);
      rs += __shfl_xor(rs, 32);
      if (q == 0) atomicAdd(&snorm[z * 2048 + row], rs);
    }
  }
}

extern "C" void kernel_launch(void* const* d_in, const int* in_sizes, int n_in,
                              void* d_out, int out_size, void* d_ws, size_t ws_size,
                              hipStream_t stream) {
  const float* X    = (const float*)d_in[0];
  const float* Wk_w = (const float*)d_in[1];
  const float* Wk_b = (const float*)d_in[2];
  const float* Wq_w = (const float*)d_in[3];
  const float* Wq_b = (const float*)d_in[4];
  float* out = (float*)d_out;

  // ws: [0,32M): XT bf16 [n][b][c] -> later Xbf bf16 [n][c][b]
  //     [32M,96M): YT bf16 [n][k][b] (holds E=exp after GEMM-Y)
  //     [96M+): DK2, DQ2, SNORM, Wk_bf, Wq_bf, bk_bf, bq_bf
  char* ws = (char*)d_ws;
  __bf16* XT  = (__bf16*)(ws);
  __bf16* Xbf = (__bf16*)(ws);
  __bf16* YT  = (__bf16*)(ws + 33554432L);
  char* aux   = ws + 100663296L;
  float*  DK2   = (float*)(aux);
  float*  DQ2   = (float*)(aux + 65536L);
  float*  SNORM = (float*)(aux + 131072L);
  __bf16* Wk_bf = (__bf16*)(aux + 196608L);
  __bf16* Wq_bf = (__bf16*)(aux + 196608L + 2097152L);
  __bf16* bk_bf = (__bf16*)(aux + 196608L + 4194304L);
  __bf16* bq_bf = (__bf16*)(aux + 196608L + 4196352L);
  // d_out (64 MiB) holds KT|QT until GEMM3 overwrites it with Z.
  __bf16* KT = (__bf16*)d_out;
  __bf16* QT = (__bf16*)((char*)d_out + 33554432L);

  // 0) convert weights/biases to bf16; zero DK2|DQ2|SNORM (contiguous 192 KiB)
  cvt_bf16<<<1024, 256, 0, stream>>>(Wk_w, Wk_bf, 1048576L);
  cvt_bf16<<<1024, 256, 0, stream>>>(Wq_w, Wq_bf, 1048576L);
  cvt_bf16<<<1, 256, 0, stream>>>(Wk_b, bk_bf, 1024L);
  cvt_bf16<<<1, 256, 0, stream>>>(Wq_b, bq_bf, 1024L);
  zero_f32<<<48, 256, 0, stream>>>(DK2, 49152L);
  // 1) XT[n][b][c] = (bf16) X[n][c][b]
  cvt_transpose<<<dim3(32, 16, 8), 256, 0, stream>>>(X, XT);
  // 2) KT[n][b][o] = XT[b,:]·Wk[o,:] + bk[o]; fused rownorm -> DK2; same for Q
  gemm256<1024, 0, __bf16><<<dim3(4, 8, 8), 512, 0, stream>>>(
      XT, Wk_bf, KT, bk_bf, DK2, nullptr, nullptr, 2048L * 1024, 0L, 2048L * 1024);
  gemm256<1024, 0, __bf16><<<dim3(4, 8, 8), 512, 0, stream>>>(
      XT, Wq_bf, QT, bq_bf, DQ2, nullptr, nullptr, 2048L * 1024, 0L, 2048L * 1024);
  // 3) Xbf = (bf16) X  (XT dead; same ws region)
  cvt_bf16<<<16384, 256, 0, stream>>>(X, Xbf, 16777216L);
  // 4) YT[n][k][b] = exp(clamp(cosine-score)); fused row-sum -> SNORM[n][k]
  gemm256<1024, 1, __bf16><<<dim3(8, 8, 8), 512, 0, stream>>>(
      KT, QT, YT, nullptr, DK2, DQ2, SNORM, 2048L * 1024, 2048L * 1024,
      2048L * 2048);
  // 5) Z[n][c][k] = (Xbf[c,:]·E[k,:]) / SNORM[k]  -> d_out fp32
  gemm256<2048, 2, float><<<dim3(8, 4, 8), 512, 0, stream>>>(
      Xbf, YT, out, nullptr, nullptr, SNORM, nullptr, 1024L * 2048,
      2048L * 2048, 1024L * 2048);
}